// Round 11
// baseline (182.845 us; speedup 1.0000x reference)
//
#include <hip/hip_runtime.h>
#include <hip/hip_bf16.h>
#include <hip/hip_fp16.h>
#include <math.h>

#define NB  8
#define CIN 64
#define HH  112
#define WW  112
#define OC  64
#define HWSZ (HH*WW)
#define NPOS (NB*HWSZ)

typedef unsigned short u16;
typedef __attribute__((ext_vector_type(8))) short short8;
typedef __attribute__((ext_vector_type(4))) float floatx4;

#define XT_ELEMS   (NB*HWSZ*CIN)   // 6,422,528 u16 (12.25 MB)
#define WSWZ_ELEMS (18*4*64*8)     // 36,864 u16
#define OSWZ_ELEMS (18*4*32*8)     // 18,432 u16

__device__ __forceinline__ u16 f2bf(float f) {
    unsigned int i = __float_as_uint(f);
    unsigned int r = i + 0x7fffu + ((i >> 16) & 1u);   // RNE
    return (u16)(r >> 16);
}
__device__ __forceinline__ unsigned pk2bf(float lo, float hi) {
    union { __hip_bfloat162 b; unsigned u; } cv;
    cv.b = __float22bfloat162_rn(float2{lo, hi});      // v_cvt_pk_bf16_f32
    return cv.u;
}
#define BLO(uu) __uint_as_float((uu) << 16)
#define BHI(uu) __uint_as_float((uu) & 0xffff0000u)

union CV { uint4 u; short8 s; };

struct Tap { int o00, o01, o10, o11; float w00, w01, w10, w11; };
struct G8 { uint4  a0,a1,a2,a3,a4,a5,a6,a7; };
struct W8 { short8 b0,b1,b2,b3,b4,b5,b6,b7; };

__device__ __forceinline__ Tap unpackP(uint4 P) {
    Tap t;
    const int o00 = (int)(P.x & 0xFFFFFu);
    const int dx  = (int)((P.x >> 30) & 1u) << 6;      // 0 or 64  (=CIN)
    const int dy  = (int)(P.x >> 31) * (WW*CIN);       // 0 or 7168
    t.o00 = o00; t.o01 = o00 + dx; t.o10 = o00 + dy; t.o11 = o00 + dx + dy;
    t.w00 = __half2float(__ushort_as_half((u16)(P.y & 0xFFFFu)));
    t.w01 = __half2float(__ushort_as_half((u16)(P.y >> 16)));
    t.w10 = __half2float(__ushort_as_half((u16)(P.z & 0xFFFFu)));
    t.w11 = __half2float(__ushort_as_half((u16)(P.z >> 16)));
    return t;
}

// pinned 16B loads the compiler cannot sink (untied outputs — these compile)
__device__ __forceinline__ void gld4(uint4 &d, const u16* p) {
    asm volatile("global_load_dwordx4 %0, %1, off" : "=v"(d) : "v"(p));
}
__device__ __forceinline__ void gldw(short8 &d, const u16* p) {
    asm volatile("global_load_dwordx4 %0, %1, off" : "=v"(d) : "v"(p));
}

// manual vmcnt gate: no tied operands; sched_barrier(0) pins scheduling
#define VMW(N_) { \
    __builtin_amdgcn_sched_barrier(0); \
    asm volatile("s_waitcnt vmcnt(" #N_ ")" ::: "memory"); \
    __builtin_amdgcn_sched_barrier(0); }

// ---------- prep: NCHW fp32 -> NHWC bf16 transpose of x, plus weight swizzle ----------
__global__ __launch_bounds__(256) void transpose_k(
    const float* __restrict__ x, u16* __restrict__ xt,
    const float* __restrict__ wgt, const float* __restrict__ offw,
    u16* __restrict__ wswz, u16* __restrict__ oswz)
{
    const int tid = threadIdx.x;
    if (blockIdx.x == HWSZ/64) {
        const int base = blockIdx.y * ((WSWZ_ELEMS + OSWZ_ELEMS)/NB);
        #pragma unroll
        for (int i = 0; i < 27; ++i) {
            const int gid = base + i*256 + tid;
            if (gid < WSWZ_ELEMS) {
                const int j = gid & 7, o = (gid >> 3) & 63, qq = (gid >> 9) & 3, s = gid >> 11;
                const int k = s*32 + qq*8 + j;
                const int c = k & 63, t = k >> 6;
                wswz[gid] = f2bf(wgt[o*576 + c*9 + t]);
            } else {
                const int g2 = gid - WSWZ_ELEMS;
                const int j = g2 & 7, r = (g2 >> 3) & 31, qq = (g2 >> 8) & 3, s = g2 >> 10;
                const int k = s*32 + qq*8 + j;
                const int c = k & 63, t = k >> 6;
                oswz[g2] = (r < 27) ? f2bf(offw[r*576 + c*9 + t]) : (u16)0;
            }
        }
        return;
    }
    __shared__ float t[64][65];
    const int n   = blockIdx.y;
    const int hw0 = blockIdx.x * 64;
    const int wv  = tid & 63;
    const int g   = tid >> 6;
    #pragma unroll
    for (int i = 0; i < 16; ++i) {
        const int c = i*4 + g;
        t[c][wv] = x[((size_t)n*CIN + c)*HWSZ + hw0 + wv];
    }
    __syncthreads();
    #pragma unroll
    for (int i = 0; i < 4; ++i) {
        const int unit = i*256 + tid;
        const int cg = unit & 15;
        const int hw = unit >> 4;
        uint2 o;
        o.x = pk2bf(t[cg*4+0][hw], t[cg*4+1][hw]);
        o.y = pk2bf(t[cg*4+2][hw], t[cg*4+3][hw]);
        *(uint2*)(xt + ((size_t)n*HWSZ + hw0 + hw)*CIN + cg*4) = o;
    }
}

#define IM2COL_LOAD(DST, S_) { \
    const int t_ = (S_) >> 1; \
    const int ty_ = t_/3, tx_ = t_ - 3*ty_; \
    const int y_ = ho - 1 + ty_, xx_ = wo0 + m - 1 + tx_; \
    const int ch_ = ((S_) & 1)*32 + q*8; \
    uint4 v_ = {0u,0u,0u,0u}; \
    if (((unsigned)y_ < HH) && ((unsigned)xx_ < WW)) \
        v_ = *(const uint4*)(xtn + (y_*WW + xx_)*CIN + ch_); \
    DST = v_; }

#define OFF_MFMA(SRC, S_) { CV cb_; cb_.u = (SRC); \
    const u16* ap_ = oswz + ((S_)*4 + q)*256 + m*8; \
    acc0 = __builtin_amdgcn_mfma_f32_16x16x32_bf16(*(const short8*)(ap_),       cb_.s, acc0, 0, 0, 0); \
    acc1 = __builtin_amdgcn_mfma_f32_16x16x32_bf16(*(const short8*)(ap_ + 128), cb_.s, acc1, 0, 0, 0); }

#define ISSUE_G(GB, TP) { \
    gld4(GB.a0, xtn + (TP).o00 + ch0); \
    gld4(GB.a1, xtn + (TP).o01 + ch0); \
    gld4(GB.a2, xtn + (TP).o10 + ch0); \
    gld4(GB.a3, xtn + (TP).o11 + ch0); \
    gld4(GB.a4, xtn + (TP).o00 + ch1); \
    gld4(GB.a5, xtn + (TP).o01 + ch1); \
    gld4(GB.a6, xtn + (TP).o10 + ch1); \
    gld4(GB.a7, xtn + (TP).o11 + ch1); }

#define ISSUE_W(WB, T_) { \
    const u16* wpa_ = wswz + ((2*(T_))*4 + q)*512 + m*8; \
    const u16* wpb_ = wswz + ((2*(T_)+1)*4 + q)*512 + m*8; \
    gldw(WB.b0, wpa_);       gldw(WB.b1, wpa_ + 128); \
    gldw(WB.b2, wpa_ + 256); gldw(WB.b3, wpa_ + 384); \
    gldw(WB.b4, wpb_);       gldw(WB.b5, wpb_ + 128); \
    gldw(WB.b6, wpb_ + 256); gldw(WB.b7, wpb_ + 384); }

#define HSTEP(R00, R01, R10, R11, TP, WA, WBm, WC, WD) { \
    const float w00 = (TP).w00, w01 = (TP).w01, w10 = (TP).w10, w11 = (TP).w11; \
    float v0 = w00*BLO((R00).x) + w01*BLO((R01).x) + w10*BLO((R10).x) + w11*BLO((R11).x); \
    float v1 = w00*BHI((R00).x) + w01*BHI((R01).x) + w10*BHI((R10).x) + w11*BHI((R11).x); \
    float v2 = w00*BLO((R00).y) + w01*BLO((R01).y) + w10*BLO((R10).y) + w11*BLO((R11).y); \
    float v3 = w00*BHI((R00).y) + w01*BHI((R01).y) + w10*BHI((R10).y) + w11*BHI((R11).y); \
    float v4 = w00*BLO((R00).z) + w01*BLO((R01).z) + w10*BLO((R10).z) + w11*BLO((R11).z); \
    float v5 = w00*BHI((R00).z) + w01*BHI((R01).z) + w10*BHI((R10).z) + w11*BHI((R11).z); \
    float v6 = w00*BLO((R00).w) + w01*BLO((R01).w) + w10*BLO((R10).w) + w11*BLO((R11).w); \
    float v7 = w00*BHI((R00).w) + w01*BHI((R01).w) + w10*BHI((R10).w) + w11*BHI((R11).w); \
    CV cb_; \
    cb_.u.x = pk2bf(v0, v1); cb_.u.y = pk2bf(v2, v3); \
    cb_.u.z = pk2bf(v4, v5); cb_.u.w = pk2bf(v6, v7); \
    acc[0] = __builtin_amdgcn_mfma_f32_16x16x32_bf16((WA),  cb_.s, acc[0], 0, 0, 0); \
    acc[1] = __builtin_amdgcn_mfma_f32_16x16x32_bf16((WBm), cb_.s, acc[1], 0, 0, 0); \
    acc[2] = __builtin_amdgcn_mfma_f32_16x16x32_bf16((WC),  cb_.s, acc[2], 0, 0, 0); \
    acc[3] = __builtin_amdgcn_mfma_f32_16x16x32_bf16((WD),  cb_.s, acc[3], 0, 0, 0); }

// consume tap T_ from (GB,WB,TPC), refill with tap T_+2; literal indices only
#define STEP_MID(T_, GB, WB, TPC) { \
    VMW(16) \
    HSTEP(GB.a0, GB.a1, GB.a2, GB.a3, TPC, WB.b0, WB.b1, WB.b2, WB.b3) \
    HSTEP(GB.a4, GB.a5, GB.a6, GB.a7, TPC, WB.b4, WB.b5, WB.b6, WB.b7) \
    Tap tn_ = unpackP(Pn); \
    ISSUE_G(GB, tn_) \
    ISSUE_W(WB, (T_)+2) \
    TPC = tn_; \
    Pn = prm[wid][(T_)+3][m]; }

// ---------- fused: offset conv + sampling + main conv ----------
__global__ __launch_bounds__(256)
__attribute__((amdgpu_waves_per_eu(2, 4)))
void dcn_k(
    const u16*  __restrict__ xt,
    const u16*  __restrict__ wswz,
    const u16*  __restrict__ oswz,
    const float* __restrict__ bias,
    const float* __restrict__ offb,
    float* __restrict__ out)
{
    __shared__ float raws[4][32][16];
    __shared__ uint4 prm[4][9][16];

    const int tid  = threadIdx.x;
    const int lane = tid & 63;
    const int wid  = tid >> 6;
    const int m    = lane & 15;
    const int q    = lane >> 4;

    const int n     = blockIdx.x & 7;                     // XCD-locality swizzle
    const int rem64 = ((blockIdx.x >> 3)*4 + wid) * 16;   // 16 positions, one row
    const int ho  = rem64 / WW;
    const int wo0 = rem64 - ho*WW;
    const u16* xtn = xt + (size_t)n * HWSZ * CIN;

    // ---- phase 1+2: im2col loads + offset conv (compiler-scheduled; drains at barrier) ----
    {
        uint4 buA[6], buB[6];
        #pragma unroll
        for (int s = 0; s < 6; ++s) IM2COL_LOAD(buA[s], s)
        #pragma unroll
        for (int s = 0; s < 6; ++s) IM2COL_LOAD(buB[s], s + 6)

        floatx4 acc0 = {0.f,0.f,0.f,0.f}, acc1 = {0.f,0.f,0.f,0.f};
        #pragma unroll
        for (int s = 0; s < 6; ++s) {
            uint4 nv; IM2COL_LOAD(nv, s + 12)
            OFF_MFMA(buA[s], s)
            buA[s] = nv;
        }
        #pragma unroll
        for (int s = 0; s < 6; ++s) OFF_MFMA(buB[s], s + 6)
        #pragma unroll
        for (int s = 0; s < 6; ++s) OFF_MFMA(buA[s], s + 12)

        #pragma unroll
        for (int r = 0; r < 4; ++r) {
            raws[wid][q*4 + r][m]      = acc0[r];
            raws[wid][16 + q*4 + r][m] = acc1[r];
        }
    }
    __syncthreads();

    // ---- phase 3: packed tap params (mask & border zeroing folded into weights) ----
    #pragma unroll
    for (int i = 0; i < 3; ++i) {
        const int e = i*64 + lane;
        if (e < 144) {
            const int t = e >> 4;        // 0..8
            const int p = e & 15;
            const int ty = t / 3, tx = t - 3*ty;
            const float py = raws[wid][2*t][p]     + offb[2*t]     + (float)(ho - 1 + ty);
            const float px = raws[wid][2*t + 1][p] + offb[2*t + 1] + (float)(wo0 + p - 1 + tx);
            const float mk = 1.f / (1.f + expf(-(raws[wid][18 + t][p] + offb[18 + t])));
            const float y0f = floorf(py), x0f = floorf(px);
            const float fy = py - y0f, fx = px - x0f;
            const int y0 = (int)y0f, x0 = (int)x0f;
            const float gy = 1.f - fy, gx = 1.f - fx;
            const bool vy0 = (unsigned)y0       < HH;
            const bool vy1 = (unsigned)(y0 + 1) < HH;
            const bool vx0 = (unsigned)x0       < WW;
            const bool vx1 = (unsigned)(x0 + 1) < WW;
            const float w00 = (vy0 && vx0) ? gy*gx*mk : 0.f;
            const float w01 = (vy0 && vx1) ? gy*fx*mk : 0.f;
            const float w10 = (vy1 && vx0) ? fy*gx*mk : 0.f;
            const float w11 = (vy1 && vx1) ? fy*fx*mk : 0.f;
            const int yc0 = min(max(y0, 0), HH-1),  yc1 = min(max(y0+1, 0), HH-1);
            const int xc0 = min(max(x0, 0), WW-1),  xc1 = min(max(x0+1, 0), WW-1);
            const unsigned o00 = (unsigned)((yc0*WW + xc0)*CIN);
            const unsigned dxb = (unsigned)(xc1 - xc0);   // 0/1
            const unsigned dyb = (unsigned)(yc1 - yc0);   // 0/1
            uint4 P;
            P.x = o00 | (dxb << 30) | (dyb << 31);
            P.y = (unsigned)__half_as_ushort(__float2half(w00))
                | ((unsigned)__half_as_ushort(__float2half(w01)) << 16);
            P.z = (unsigned)__half_as_ushort(__float2half(w10))
                | ((unsigned)__half_as_ushort(__float2half(w11)) << 16);
            P.w = 0u;
            prm[wid][t][p] = P;
        }
    }
    __syncthreads();   // all compiler vmem drained here (barrier forces vmcnt(0))

    // ---- phase 4: asm-pinned 2-tap-deep pipeline; 32 loads in flight ----
    floatx4 acc[4];
    #pragma unroll
    for (int i = 0; i < 4; ++i) acc[i] = (floatx4){0.f,0.f,0.f,0.f};

    const int ch0 = q*8, ch1 = 32 + q*8;
    G8 G0, G1;
    W8 W0, W1;
    Tap t0, t1;

    t0 = unpackP(prm[wid][0][m]);
    ISSUE_G(G0, t0)
    ISSUE_W(W0, 0)
    t1 = unpackP(prm[wid][1][m]);
    ISSUE_G(G1, t1)
    ISSUE_W(W1, 1)
    uint4 Pn = prm[wid][2][m];

    STEP_MID(0, G0, W0, t0)
    STEP_MID(1, G1, W1, t1)
    STEP_MID(2, G0, W0, t0)
    STEP_MID(3, G1, W1, t1)
    STEP_MID(4, G0, W0, t0)
    STEP_MID(5, G1, W1, t1)
    // t = 6: consume G0, refill with tap 8 (no Pn advance — prm[9] doesn't exist)
    {
        VMW(16)
        HSTEP(G0.a0, G0.a1, G0.a2, G0.a3, t0, W0.b0, W0.b1, W0.b2, W0.b3)
        HSTEP(G0.a4, G0.a5, G0.a6, G0.a7, t0, W0.b4, W0.b5, W0.b6, W0.b7)
        Tap tn_ = unpackP(Pn);
        ISSUE_G(G0, tn_)
        ISSUE_W(W0, 8)
        t0 = tn_;
    }
    // t = 7: consume G1, no refill
    {
        VMW(16)
        HSTEP(G1.a0, G1.a1, G1.a2, G1.a3, t1, W1.b0, W1.b1, W1.b2, W1.b3)
        HSTEP(G1.a4, G1.a5, G1.a6, G1.a7, t1, W1.b4, W1.b5, W1.b6, W1.b7)
    }
    // t = 8: consume G0, full drain
    {
        VMW(0)
        HSTEP(G0.a0, G0.a1, G0.a2, G0.a3, t0, W0.b0, W0.b1, W0.b2, W0.b3)
        HSTEP(G0.a4, G0.a5, G0.a6, G0.a7, t0, W0.b4, W0.b5, W0.b6, W0.b7)
    }
    asm volatile("" ::: "memory");            // keep epilogue vmem below final drain

    // ---- epilogue ----
    #pragma unroll
    for (int ob = 0; ob < 4; ++ob) {
        #pragma unroll
        for (int r = 0; r < 4; ++r) {
            const int o = ob*16 + q*4 + r;
            out[(((size_t)n*OC + o)*HH + ho)*WW + wo0 + m] = acc[ob][r] + bias[o];
        }
    }
}

extern "C" void kernel_launch(void* const* d_in, const int* in_sizes, int n_in,
                              void* d_out, int out_size, void* d_ws, size_t ws_size,
                              hipStream_t stream)
{
    const float* x    = (const float*)d_in[0];
    const float* wgt  = (const float*)d_in[1];
    const float* bias = (const float*)d_in[2];
    const float* offw = (const float*)d_in[3];
    const float* offb = (const float*)d_in[4];
    float* out = (float*)d_out;

    u16* xt   = (u16*)d_ws;
    u16* wswz = xt + XT_ELEMS;
    u16* oswz = wswz + WSWZ_ELEMS;

    transpose_k<<<dim3(HWSZ/64 + 1, NB), 256, 0, stream>>>(x, xt, wgt, offw, wswz, oswz);
    dcn_k<<<dim3(NPOS/64), 256, 0, stream>>>(xt, wswz, oswz, bias, offb, out);
}